// Round 4
// baseline (742.965 us; speedup 1.0000x reference)
//
#include <hip/hip_runtime.h>
#include <hip/hip_bf16.h>

// Problem constants (from reference)
#define N_TRIALS   8
#define T_TOTAL    600
#define N_NEURONS  30000
#define T_USE      500          // T_END - T_START
#define N_SAMPLES  50
#define MAX_COUNT  200
#define N_BINS     16
#define MAXP       (N_SAMPLES * MAX_COUNT)  // worst-case pairs per trial (10000)
#define SORT_MAX   8192                     // max in-LDS sort size (32 KB)
#define EPS_D      1e-7

__device__ __constant__ int BIN_SIZES[N_BINS] = {1,1,2,3,4,6,9,13,18,26,38,55,78,113,162,234};

// K0: build per-trial (neuron,sample) pair lists. mask is a prefix mask, but we
// just test mask!=0 per slot. Key = (neuron<<6)|sample (neuron<25000, sample<50).
__global__ __launch_bounds__(256) void build_pairs(
    const int*   __restrict__ trials,
    const int*   __restrict__ ids,
    const float* __restrict__ mask,
    unsigned*    __restrict__ pairs,   // [N_TRIALS][MAXP]
    int*         __restrict__ npairs)  // [N_TRIALS]
{
    __shared__ int np[N_TRIALS];
    int tid = threadIdx.x;
    if (tid < N_TRIALS) np[tid] = 0;
    __syncthreads();
    for (int f = tid; f < N_SAMPLES * MAX_COUNT; f += 256) {
        if (mask[f] != 0.f) {
            int s  = f / MAX_COUNT;
            int tr = trials[s];
            int pos = atomicAdd(&np[tr], 1);
            pairs[tr * MAXP + pos] = ((unsigned)ids[f] << 6) | (unsigned)s;
        }
    }
    __syncthreads();
    if (tid < N_TRIALS) npairs[tid] = np[tid];
}

// K1: per-trial in-LDS bitonic sort of the pair list (ascending neuron order ->
// ascending gather addresses). Sorting is a PERF optimization only; correctness
// does not depend on order, so np>SORT_MAX (never with this data) just skips.
__global__ __launch_bounds__(256) void sort_pairs(
    unsigned* __restrict__ pairs, const int* __restrict__ npairs)
{
    __shared__ unsigned buf[SORT_MAX];
    int tr = blockIdx.x;
    int np = npairs[tr];
    if (np <= 1 || np > SORT_MAX) return;
    int m = 2; while (m < np) m <<= 1;
    int tid = threadIdx.x;
    unsigned* p = pairs + tr * MAXP;
    for (int i = tid; i < m; i += 256) buf[i] = (i < np) ? p[i] : 0xFFFFFFFFu;
    __syncthreads();
    for (int k = 2; k <= m; k <<= 1) {
        for (int j = k >> 1; j > 0; j >>= 1) {
            for (int i = tid; i < m; i += 256) {
                int ixj = i ^ j;
                if (ixj > i) {
                    unsigned a = buf[i], b = buf[ixj];
                    bool up = ((i & k) == 0);
                    if ((a > b) == up) { buf[i] = b; buf[ixj] = a; }
                }
            }
            __syncthreads();
        }
    }
    for (int i = tid; i < np; i += 256) p[i] = buf[i];
}

// K2: one wave per (trial,t) row. Lanes stride the trial's SORTED pair list ->
// ascending addresses within each 64-lane step (coalescer merges same-line,
// DRAM sees sorted gappy bursts). Spikes are 0/1 with 2% density, so the LDS
// atomic add fires ~9x per row total.
__global__ __launch_bounds__(256) void gather_kernel(
    const float*    __restrict__ spikes,
    const unsigned* __restrict__ pairs,
    const int*      __restrict__ npairs,
    const int*      __restrict__ trials,
    float*          __restrict__ sel)
{
    __shared__ float acc[4][N_SAMPLES];
    int w    = threadIdx.x >> 6;
    int lane = threadIdx.x & 63;
    int r  = blockIdx.x * 4 + w;       // row id, 0..N_TRIALS*T_USE-1
    int tr = r / T_USE;
    int t  = r % T_USE;
    if (lane < N_SAMPLES) acc[w][lane] = 0.f;
    __syncthreads();

    int np = npairs[tr];
    const unsigned* pp  = pairs + tr * MAXP;
    const float*    row = spikes + ((size_t)tr * T_TOTAL + t) * N_NEURONS;
    for (int k = lane; k < np; k += 64) {
        unsigned pr = pp[k];
        float v = row[pr >> 6];
        if (v != 0.f) atomicAdd(&acc[w][pr & 63], v);
    }
    __syncthreads();

    if (lane < N_SAMPLES && trials[lane] == tr)
        sel[lane * T_USE + t] = acc[w][lane];
}

// K3: one wave per (bin, sample): bin the 500-long row, population var/mean ->
// fano[bin*50+s]. Lanes parallelize over the nb bins.
__global__ __launch_bounds__(256) void fano_stage(
    const float* __restrict__ sel,
    float*       __restrict__ fano)
{
    int w    = (blockIdx.x * 256 + threadIdx.x) >> 6;
    int lane = threadIdx.x & 63;
    if (w >= N_BINS * N_SAMPLES) return;
    int bin = w / N_SAMPLES;
    int s   = w % N_SAMPLES;
    int bs  = BIN_SIZES[bin];
    int nb  = T_USE / bs;
    const float* rowp = sel + s * T_USE;

    double sum = 0.0, sumsq = 0.0;
    for (int b = lane; b < nb; b += 64) {
        double c = 0.0;
        int base = b * bs;
        for (int q = 0; q < bs; ++q) c += (double)rowp[base + q];
        sum   += c;
        sumsq += c * c;
    }
    for (int k = 32; k; k >>= 1) {
        sum   += __shfl_xor(sum,   k);
        sumsq += __shfl_xor(sumsq, k);
    }
    if (lane == 0) {
        double mean = sum / nb;
        double var  = sumsq / nb - mean * mean;
        double m2   = mean < EPS_D ? EPS_D : mean;
        fano[w] = (float)(var / m2);
    }
}

// K4: fanos_mean per bin, MSE vs experimental, out = 10*mse. One wave.
__global__ void final_kernel(
    const float* __restrict__ fano,
    const float* __restrict__ expf,
    float*       __restrict__ out)
{
    int tid = threadIdx.x;   // 64 threads
    double d2 = 0.0;
    if (tid < N_BINS) {
        double acc = 0.0;
        for (int s = 0; s < N_SAMPLES; ++s) acc += (double)fano[tid * N_SAMPLES + s];
        double fm   = acc / N_SAMPLES;
        double diff = (double)expf[tid] - fm;
        d2 = diff * diff;
    }
    for (int k = 32; k; k >>= 1) d2 += __shfl_xor(d2, k);
    if (tid == 0) out[0] = (float)(10.0 * d2 / N_BINS);
}

extern "C" void kernel_launch(void* const* d_in, const int* in_sizes, int n_in,
                              void* d_out, int out_size, void* d_ws, size_t ws_size,
                              hipStream_t stream)
{
    const float* spikes = (const float*)d_in[0];   // (8, 600, 30000) f32
    const float* expf   = (const float*)d_in[1];   // (16,) f32
    const int*   trials = (const int*)d_in[2];     // (50,) i32
    const int*   ids    = (const int*)d_in[3];     // (50, 200) i32 (harness-converted)
    const float* mask   = (const float*)d_in[4];   // (50, 200) f32
    float* out = (float*)d_out;

    float*    sel    = (float*)d_ws;                          // 25000 f32
    float*    fano   = sel + N_SAMPLES * T_USE;               // 800 f32
    unsigned* pairs  = (unsigned*)(fano + N_BINS * N_SAMPLES);// 8*10000 u32
    int*      npairs = (int*)(pairs + N_TRIALS * MAXP);       // 8 i32

    build_pairs<<<1, 256, 0, stream>>>(trials, ids, mask, pairs, npairs);
    sort_pairs<<<N_TRIALS, 256, 0, stream>>>(pairs, npairs);

    int rows = N_TRIALS * T_USE;                   // 4000 rows, 1 wave each
    gather_kernel<<<rows / 4, 256, 0, stream>>>(spikes, pairs, npairs, trials, sel);

    fano_stage<<<(N_BINS * N_SAMPLES * 64 + 255) / 256, 256, 0, stream>>>(sel, fano);

    final_kernel<<<1, 64, 0, stream>>>(fano, expf, out);
}

// Round 5
// 727.597 us; speedup vs baseline: 1.0211x; 1.0211x over previous
//
#include <hip/hip_runtime.h>
#include <hip/hip_bf16.h>

// Problem constants (from reference)
#define N_TRIALS   8
#define T_TOTAL    600
#define N_NEURONS  30000
#define NEED_N     25000        // sample_ids ∈ [0, 25000) (n_e); rest of row never probed
#define T_USE      500          // T_END - T_START
#define N_SAMPLES  50
#define MAX_COUNT  200
#define N_BINS     16
#define GROUPS     98           // ceil(NEED_N / 256) 256-float groups per row
#define WPR        (GROUPS * 4) // u64 words per row bitmap (392)
#define ITERS      25           // ceil(GROUPS*256 / 1024) block iterations
#define EPS_D      1e-7

__device__ __constant__ int BIN_SIZES[N_BINS] = {1,1,2,3,4,6,9,13,18,26,38,55,78,113,162,234};

// K0: cnts[s] = sum(mask[s][:]) (prefix mask -> count fully describes it).
__global__ __launch_bounds__(256) void cnt_kernel(
    const float* __restrict__ mask, int* __restrict__ cnts)
{
    int w    = (blockIdx.x * 256 + threadIdx.x) >> 6;
    int lane = threadIdx.x & 63;
    if (w >= N_SAMPLES) return;
    const float* m = mask + w * MAX_COUNT;
    float sum = 0.f;
    for (int j = lane; j < MAX_COUNT; j += 64) sum += m[j];
    for (int k = 32; k; k >>= 1) sum += __shfl_xor(sum, k);
    if (lane == 0) cnts[w] = (int)(sum + 0.5f);
}

// K1: one block per (trial, t) row. Phase 1: stream the row's first 25000
// floats (float4, fully coalesced), ballot spike bits into a 25088-bit LDS
// bitmap. Phase 2: for each sample on this trial, count = popc(ballot(bit
// probes)) over its <=200 ids. Bit addressing: for neuron n, group G=n>>8,
// component c=n&3, lane L=(n>>2)&63 -> word (G<<2)|c, bit L.
__global__ __launch_bounds__(256) void row_kernel(
    const float* __restrict__ spikes,
    const int*   __restrict__ trials,
    const int*   __restrict__ ids,
    const int*   __restrict__ cnts,
    float*       __restrict__ sel)
{
    __shared__ unsigned long long bm[WPR];
    int tid  = threadIdx.x;
    int wv   = tid >> 6;
    int lane = tid & 63;
    int r    = blockIdx.x;            // 0..N_TRIALS*T_USE-1
    int tr   = r / T_USE;
    int t    = r % T_USE;
    const float* row = spikes + ((size_t)tr * T_TOTAL + t) * N_NEURONS;

    // Phase 1: build bitmap
    for (int i = 0; i < ITERS; ++i) {
        int n0 = i * 1024 + tid * 4;
        float4 v = make_float4(0.f, 0.f, 0.f, 0.f);
        if (n0 < NEED_N)              // NEED_N % 4 == 0, so full vec is in range
            v = *reinterpret_cast<const float4*>(row + n0);
        unsigned long long b0 = __ballot(v.x != 0.f);
        unsigned long long b1 = __ballot(v.y != 0.f);
        unsigned long long b2 = __ballot(v.z != 0.f);
        unsigned long long b3 = __ballot(v.w != 0.f);
        int g = i * 4 + wv;           // 256-float group index
        if (g < GROUPS && lane == 0) {
            bm[g*4+0] = b0; bm[g*4+1] = b1; bm[g*4+2] = b2; bm[g*4+3] = b3;
        }
    }
    __syncthreads();

    // Phase 2: probe for samples mapped to this trial
    for (int s = wv; s < N_SAMPLES; s += 4) {
        if (trials[s] != tr) continue;            // wave-uniform skip
        int cnt = cnts[s];
        const int* sid = ids + s * MAX_COUNT;
        int c = 0;
        for (int base = 0; base < MAX_COUNT; base += 64) {
            int j = base + lane;
            bool pred = false;
            if (j < cnt) {
                int n = sid[j];
                unsigned long long w = bm[((n >> 8) << 2) | (n & 3)];
                pred = (w >> ((n >> 2) & 63)) & 1ull;
            }
            c += __popcll(__ballot(pred));
        }
        if (lane == 0) sel[s * T_USE + t] = (float)c;
    }
}

// K2: one wave per (bin, sample): bin the 500-long row, population var/mean ->
// fano[bin*50+s]. Lanes parallelize over the nb bins.
__global__ __launch_bounds__(256) void fano_stage(
    const float* __restrict__ sel,
    float*       __restrict__ fano)
{
    int w    = (blockIdx.x * 256 + threadIdx.x) >> 6;
    int lane = threadIdx.x & 63;
    if (w >= N_BINS * N_SAMPLES) return;
    int bin = w / N_SAMPLES;
    int s   = w % N_SAMPLES;
    int bs  = BIN_SIZES[bin];
    int nb  = T_USE / bs;
    const float* rowp = sel + s * T_USE;

    double sum = 0.0, sumsq = 0.0;
    for (int b = lane; b < nb; b += 64) {
        double c = 0.0;
        int base = b * bs;
        for (int q = 0; q < bs; ++q) c += (double)rowp[base + q];
        sum   += c;
        sumsq += c * c;
    }
    for (int k = 32; k; k >>= 1) {
        sum   += __shfl_xor(sum,   k);
        sumsq += __shfl_xor(sumsq, k);
    }
    if (lane == 0) {
        double mean = sum / nb;
        double var  = sumsq / nb - mean * mean;
        double m2   = mean < EPS_D ? EPS_D : mean;
        fano[w] = (float)(var / m2);
    }
}

// K3: fanos_mean per bin, MSE vs experimental, out = 10*mse. One wave.
__global__ void final_kernel(
    const float* __restrict__ fano,
    const float* __restrict__ expf,
    float*       __restrict__ out)
{
    int tid = threadIdx.x;   // 64 threads
    double d2 = 0.0;
    if (tid < N_BINS) {
        double acc = 0.0;
        for (int s = 0; s < N_SAMPLES; ++s) acc += (double)fano[tid * N_SAMPLES + s];
        double fm   = acc / N_SAMPLES;
        double diff = (double)expf[tid] - fm;
        d2 = diff * diff;
    }
    for (int k = 32; k; k >>= 1) d2 += __shfl_xor(d2, k);
    if (tid == 0) out[0] = (float)(10.0 * d2 / N_BINS);
}

extern "C" void kernel_launch(void* const* d_in, const int* in_sizes, int n_in,
                              void* d_out, int out_size, void* d_ws, size_t ws_size,
                              hipStream_t stream)
{
    const float* spikes = (const float*)d_in[0];   // (8, 600, 30000) f32
    const float* expf   = (const float*)d_in[1];   // (16,) f32
    const int*   trials = (const int*)d_in[2];     // (50,) i32
    const int*   ids    = (const int*)d_in[3];     // (50, 200) i32 (harness-converted)
    const float* mask   = (const float*)d_in[4];   // (50, 200) f32
    float* out = (float*)d_out;

    float* sel  = (float*)d_ws;                      // 25000 f32
    float* fano = sel + N_SAMPLES * T_USE;           // 800 f32
    int*   cnts = (int*)(fano + N_BINS * N_SAMPLES); // 50 i32

    cnt_kernel<<<(N_SAMPLES * 64 + 255) / 256, 256, 0, stream>>>(mask, cnts);

    row_kernel<<<N_TRIALS * T_USE, 256, 0, stream>>>(spikes, trials, ids, cnts, sel);

    fano_stage<<<(N_BINS * N_SAMPLES * 64 + 255) / 256, 256, 0, stream>>>(sel, fano);

    final_kernel<<<1, 64, 0, stream>>>(fano, expf, out);
}

// Round 6
// 725.050 us; speedup vs baseline: 1.0247x; 1.0035x over previous
//
#include <hip/hip_runtime.h>
#include <hip/hip_bf16.h>

typedef unsigned long long ull;

// Problem constants (from reference)
#define N_TRIALS   8
#define T_TOTAL    600
#define N_NEURONS  30000
#define NEED_N     25000        // sample_ids ∈ [0, 25000); rest of row never probed
#define T_USE      500
#define N_SAMPLES  50
#define MAX_COUNT  200
#define N_BINS     16
#define GROUPS     98           // 256-float groups per row (98*256 = 25088 >= 25000)
#define WPR        (GROUPS * 4) // u64 words per row bitmap (392)
#define QPR        (GROUPS * 64)// padded float4-quads per row (6272)
#define N_ROWS     (N_TRIALS * T_USE)              // 4000
#define TOT_QUADS  (N_ROWS * QPR)                  // 25,088,000 (= 98,000 * 256)
#define EPS_D      1e-7

__device__ __constant__ int BIN_SIZES[N_BINS] = {1,1,2,3,4,6,9,13,18,26,38,55,78,113,162,234};

// K0: cnts[s] = sum(mask[s][:]) (prefix mask -> count fully describes it).
__global__ __launch_bounds__(256) void cnt_kernel(
    const float* __restrict__ mask, int* __restrict__ cnts)
{
    int w    = (blockIdx.x * 256 + threadIdx.x) >> 6;
    int lane = threadIdx.x & 63;
    if (w >= N_SAMPLES) return;
    const float* m = mask + w * MAX_COUNT;
    float sum = 0.f;
    for (int j = lane; j < MAX_COUNT; j += 64) sum += m[j];
    for (int k = 32; k; k >>= 1) sum += __shfl_xor(sum, k);
    if (lane == 0) cnts[w] = (int)(sum + 0.5f);
}

// K1: pure-stream compress. One float4 per thread, exact grid, no LDS, no
// syncthreads. Wave w covers 64 consecutive quads (256 floats) of one row
// (QPR % 64 == 0 keeps waves row-pure and group-aligned). ballot per
// component -> 4 u64 bitmap words; lane 0 stores 2x16B.
// Bit mapping for neuron n: word = row*WPR + ((n>>8)<<2 | (n&3)), bit (n>>2)&63.
__global__ __launch_bounds__(256) void compress_kernel(
    const float* __restrict__ spikes, ull* __restrict__ bm)
{
    unsigned u = blockIdx.x * 256 + threadIdx.x;   // < TOT_QUADS
    unsigned q = u % QPR;                           // quad within row
    unsigned r = u / QPR;                           // row id = tr*T_USE + t
    unsigned tr = r / T_USE;                        // wave-uniform
    unsigned rowg = r + tr * (T_TOTAL - T_USE);     // tr*600 + t

    float4 v = make_float4(0.f, 0.f, 0.f, 0.f);
    if (q < NEED_N / 4)                             // pad quads stay zero
        v = *reinterpret_cast<const float4*>(spikes + (size_t)rowg * N_NEURONS + q * 4);

    ull b0 = __ballot(v.x != 0.f);
    ull b1 = __ballot(v.y != 0.f);
    ull b2 = __ballot(v.z != 0.f);
    ull b3 = __ballot(v.w != 0.f);

    if ((threadIdx.x & 63) == 0) {
        ull* dst = bm + (size_t)r * WPR + (q >> 6) * 4;   // q>>6 wave-uniform
        ulonglong2 p0; p0.x = b0; p0.y = b1;
        ulonglong2 p1; p1.x = b2; p1.y = b3;
        *reinterpret_cast<ulonglong2*>(dst)     = p0;
        *reinterpret_cast<ulonglong2*>(dst + 2) = p1;
    }
}

// K2: one block per t. Stage all 8 trial-row bitmaps (25 KB) into LDS
// (coalesced), then each wave computes counts for samples s = wv, wv+4, ...
// via LDS bit probes + popc(ballot). No scattered HBM traffic at all.
__global__ __launch_bounds__(256) void probe_kernel(
    const ull* __restrict__ bm,
    const int* __restrict__ trials,
    const int* __restrict__ ids,
    const int* __restrict__ cnts,
    float*     __restrict__ sel)
{
    __shared__ ull lbm[N_TRIALS][WPR];
    int t    = blockIdx.x;
    int tid  = threadIdx.x;
    int wv   = tid >> 6;
    int lane = tid & 63;

    for (int tr = 0; tr < N_TRIALS; ++tr)
        for (int j = tid; j < WPR; j += 256)
            lbm[tr][j] = bm[(size_t)(tr * T_USE + t) * WPR + j];
    __syncthreads();

    for (int s = wv; s < N_SAMPLES; s += 4) {
        int tr  = trials[s];
        int cnt = cnts[s];
        const int* sid = ids + s * MAX_COUNT;
        int c = 0;
        for (int base = 0; base < MAX_COUNT; base += 64) {
            int j = base + lane;
            bool pred = false;
            if (j < cnt) {
                int n = sid[j];
                ull w = lbm[tr][((n >> 8) << 2) | (n & 3)];
                pred = (w >> ((n >> 2) & 63)) & 1ull;
            }
            c += __popcll(__ballot(pred));
        }
        if (lane == 0) sel[s * T_USE + t] = (float)c;
    }
}

// K3: one wave per (bin, sample): population var/mean -> fano[bin*50+s].
__global__ __launch_bounds__(256) void fano_stage(
    const float* __restrict__ sel,
    float*       __restrict__ fano)
{
    int w    = (blockIdx.x * 256 + threadIdx.x) >> 6;
    int lane = threadIdx.x & 63;
    if (w >= N_BINS * N_SAMPLES) return;
    int bin = w / N_SAMPLES;
    int s   = w % N_SAMPLES;
    int bs  = BIN_SIZES[bin];
    int nb  = T_USE / bs;
    const float* rowp = sel + s * T_USE;

    double sum = 0.0, sumsq = 0.0;
    for (int b = lane; b < nb; b += 64) {
        double c = 0.0;
        int base = b * bs;
        for (int q = 0; q < bs; ++q) c += (double)rowp[base + q];
        sum   += c;
        sumsq += c * c;
    }
    for (int k = 32; k; k >>= 1) {
        sum   += __shfl_xor(sum,   k);
        sumsq += __shfl_xor(sumsq, k);
    }
    if (lane == 0) {
        double mean = sum / nb;
        double var  = sumsq / nb - mean * mean;
        double m2   = mean < EPS_D ? EPS_D : mean;
        fano[w] = (float)(var / m2);
    }
}

// K4: fanos_mean per bin, MSE vs experimental, out = 10*mse. One wave.
__global__ void final_kernel(
    const float* __restrict__ fano,
    const float* __restrict__ expf,
    float*       __restrict__ out)
{
    int tid = threadIdx.x;   // 64 threads
    double d2 = 0.0;
    if (tid < N_BINS) {
        double acc = 0.0;
        for (int s = 0; s < N_SAMPLES; ++s) acc += (double)fano[tid * N_SAMPLES + s];
        double fm   = acc / N_SAMPLES;
        double diff = (double)expf[tid] - fm;
        d2 = diff * diff;
    }
    for (int k = 32; k; k >>= 1) d2 += __shfl_xor(d2, k);
    if (tid == 0) out[0] = (float)(10.0 * d2 / N_BINS);
}

extern "C" void kernel_launch(void* const* d_in, const int* in_sizes, int n_in,
                              void* d_out, int out_size, void* d_ws, size_t ws_size,
                              hipStream_t stream)
{
    const float* spikes = (const float*)d_in[0];   // (8, 600, 30000) f32
    const float* expf   = (const float*)d_in[1];   // (16,) f32
    const int*   trials = (const int*)d_in[2];     // (50,) i32
    const int*   ids    = (const int*)d_in[3];     // (50, 200) i32 (harness-converted)
    const float* mask   = (const float*)d_in[4];   // (50, 200) f32
    float* out = (float*)d_out;

    ull*   bm   = (ull*)d_ws;                      // 4000*392 u64 = 12.544 MB
    float* sel  = (float*)(bm + (size_t)N_ROWS * WPR); // 25000 f32
    float* fano = sel + N_SAMPLES * T_USE;         // 800 f32
    int*   cnts = (int*)(fano + N_BINS * N_SAMPLES); // 50 i32

    cnt_kernel<<<(N_SAMPLES * 64 + 255) / 256, 256, 0, stream>>>(mask, cnts);

    compress_kernel<<<TOT_QUADS / 256, 256, 0, stream>>>(spikes, bm);

    probe_kernel<<<T_USE, 256, 0, stream>>>(bm, trials, ids, cnts, sel);

    fano_stage<<<(N_BINS * N_SAMPLES * 64 + 255) / 256, 256, 0, stream>>>(sel, fano);

    final_kernel<<<1, 64, 0, stream>>>(fano, expf, out);
}